// Round 21
// baseline (95.551 us; speedup 1.0000x reference)
//
#include <hip/hip_runtime.h>

#define XD 512
#define HEADS 8
#define DH 64
#define NSEQ 2048
#define NBATCH 4
#define NROWS (NBATCH*NSEQ)   // 8192

#define SCALE_L2E 0.18033688011112042f   // 0.125 * log2(e)
#define DEFER_THR 4.0f

typedef __attribute__((ext_vector_type(8))) short bf16x8;
typedef __attribute__((ext_vector_type(8))) unsigned short u16x8;
typedef __attribute__((ext_vector_type(4))) float f32x4;
typedef __attribute__((ext_vector_type(16))) float f32x16;

__device__ __forceinline__ unsigned short f2bf(float f) {
  union { float f; unsigned u; } v; v.f = f;
  return (unsigned short)((v.u + 0x7fffu + ((v.u >> 16) & 1u)) >> 16);
}

__device__ __forceinline__ float fexp2(float x) {
#if __has_builtin(__builtin_amdgcn_exp2f)
  return __builtin_amdgcn_exp2f(x);
#else
  return exp2f(x);
#endif
}

__device__ __forceinline__ unsigned cvt_pk_bf16(float lo, float hi) {
  unsigned r;
  asm("v_cvt_pk_bf16_f32 %0, %1, %2" : "=v"(r) : "v"(lo), "v"(hi));
  return r;
}

// async global->LDS, 16B per lane; LDS dest must be wave-uniform base (HW adds lane*16)
__device__ __forceinline__ void gload_lds16(const unsigned short* g, unsigned short* l) {
  __builtin_amdgcn_global_load_lds(
      (const __attribute__((address_space(1))) unsigned int*)g,
      (__attribute__((address_space(3))) unsigned int*)l, 16, 0, 0);
}

// ------- merged: weight transpose (blocks 0..1023) + z path (blocks 1024..1027) -------
__global__ __launch_bounds__(256) void wtrans4z_kernel(
    const float* __restrict__ W0, const float* __restrict__ W1,
    const float* __restrict__ W2, const float* __restrict__ W3,
    unsigned short* __restrict__ dst,
    const float* __restrict__ z, const float* __restrict__ zg, const float* __restrict__ zb,
    const float* __restrict__ Wz, float* __restrict__ z12) {
  __shared__ float tile[32][33];
  int blk = blockIdx.x;
  if (blk < 1024) {
    int w = blk >> 8;                // weight (block-uniform)
    int t = blk & 255;
    int tn = t >> 4, tk = t & 15;    // 16x16 tiles of 32x32
    const float* W = (w == 0) ? W0 : (w == 1) ? W1 : (w == 2) ? W2 : W3;
    int r = threadIdx.x >> 5, c = threadIdx.x & 31;
#pragma unroll
    for (int i = 0; i < 4; ++i)
      tile[r + 8 * i][c] = W[(size_t)(tk * 32 + r + 8 * i) * 512 + tn * 32 + c];
    __syncthreads();
    unsigned short* d = dst + (size_t)w * 262144;
#pragma unroll
    for (int i = 0; i < 4; ++i)
      d[(size_t)(tn * 32 + r + 8 * i) * 512 + tk * 32 + c] = f2bf(tile[c][r + 8 * i]);
  } else {
    int bb = blk - 1024;             // batch
    int t = threadIdx.x;
    float zv[16];
    float mean = 0.f;
#pragma unroll
    for (int i = 0; i < 16; ++i) { zv[i] = z[bb * 16 + i]; mean += zv[i]; }
    mean *= (1.f / 16.f);
    float var = 0.f;
#pragma unroll
    for (int i = 0; i < 16; ++i) { float d = zv[i] - mean; var += d * d; }
    var *= (1.f / 16.f);
    float rs = rsqrtf(var + 1e-5f);
    float zn[16];
#pragma unroll
    for (int i = 0; i < 16; ++i) zn[i] = (zv[i] - mean) * rs * zg[i] + zb[i];
    for (int c = t; c < 1024; c += 256) {
      float acc = 0.f;
#pragma unroll
      for (int i = 0; i < 16; ++i) acc += zn[i] * Wz[i * 1024 + c];
      float s = acc / (1.f + __expf(-acc));   // silu
      z12[bb * 1024 + c] = s;
    }
  }
}

// ---------------- x_mod = LN(x)*z1 + z2 -> bf16 [8192,512] ----------------
__global__ __launch_bounds__(256) void xmod_kernel(
    const float* __restrict__ x, const float* __restrict__ g, const float* __restrict__ b,
    const float* __restrict__ z12, unsigned short* __restrict__ xm) {
  int wave = threadIdx.x >> 6, lane = threadIdx.x & 63;
  int row = blockIdx.x * 4 + wave;
  const float* xr = x + (size_t)row * XD;
  float4 v0 = ((const float4*)xr)[lane * 2];
  float4 v1 = ((const float4*)xr)[lane * 2 + 1];
  float vv[8] = {v0.x, v0.y, v0.z, v0.w, v1.x, v1.y, v1.z, v1.w};
  float sum = 0.f, sq = 0.f;
#pragma unroll
  for (int i = 0; i < 8; ++i) { sum += vv[i]; sq += vv[i] * vv[i]; }
#pragma unroll
  for (int o = 32; o; o >>= 1) { sum += __shfl_xor(sum, o); sq += __shfl_xor(sq, o); }
  float mean = sum * (1.f / 512.f);
  float var = sq * (1.f / 512.f) - mean * mean;
  float rs = rsqrtf(var + 1e-5f);
  int bb = row >> 11;
  const float* zz = z12 + bb * 1024;
  int c0 = lane * 8;
  u16x8 o8;
#pragma unroll
  for (int i = 0; i < 8; ++i) {
    int c = c0 + i;
    float t = (vv[i] - mean) * rs * g[c] + b[c];
    t = t * zz[c] + zz[512 + c];
    o8[i] = f2bf(t);
  }
  *(u16x8*)(xm + (size_t)row * XD + c0) = o8;
}

// ---------- fused QKV GEMM: [8192,512] @ [512,1536], BM=128 BN=128 BK=64 ----------
// R13-proven. XCD-colocating swizzle: xcd = blk&7 owns m-tiles [xcd*8, xcd*8+8).
__global__ __launch_bounds__(256, 2) void gemm_qkv_kernel(
    const unsigned short* __restrict__ A, const unsigned short* __restrict__ Wt,
    unsigned short* __restrict__ Qo, unsigned short* __restrict__ Ko,
    unsigned short* __restrict__ Vo) {
  __shared__ unsigned short Alds[128 * 64];
  __shared__ unsigned short Blds[128 * 64];
  int widx = threadIdx.x >> 6, lane = threadIdx.x & 63;
  int blk = blockIdx.x;
  int xcd = blk & 7, local = blk >> 3;   // local 0..95
  int mt = xcd * 8 + local / 12;         // 8 consecutive m-tiles per XCD
  int nt = local % 12;
  int blkM = mt * 128, blkN = nt * 128;
  int wr = widx >> 1, wc = widx & 1;
  int lr = lane & 15, lg = lane >> 4;
  int srow = lane >> 3, sc8 = lane & 7;

  f32x4 acc[4][4] = {};

  for (int kc = 0; kc < 512; kc += 64) {
#pragma unroll
    for (int i = 0; i < 4; ++i) {
      int rb = widx * 32 + i * 8;
      int row = rb + srow;
      int cs = (sc8 ^ (row & 7)) * 8;
      gload_lds16(A + (size_t)(blkM + row) * 512 + kc + cs, &Alds[rb * 64]);
      gload_lds16(Wt + (size_t)(blkN + row) * 512 + kc + cs, &Blds[rb * 64]);
    }
    __syncthreads();

#pragma unroll
    for (int kh = 0; kh < 2; ++kh) {
      bf16x8 bfr[4];
#pragma unroll
      for (int ni = 0; ni < 4; ++ni) {
        int brow = wc * 64 + ni * 16 + lr;
        bfr[ni] = *(const bf16x8*)&Blds[brow * 64 + (((kh * 4 + lg) ^ (brow & 7)) * 8)];
      }
#pragma unroll
      for (int mi = 0; mi < 4; ++mi) {
        int arow = wr * 64 + mi * 16 + lr;
        bf16x8 afr = *(const bf16x8*)&Alds[arow * 64 + (((kh * 4 + lg) ^ (arow & 7)) * 8)];
#pragma unroll
        for (int ni = 0; ni < 4; ++ni)
          acc[mi][ni] = __builtin_amdgcn_mfma_f32_16x16x32_bf16(afr, bfr[ni], acc[mi][ni], 0, 0, 0);
      }
    }
    __syncthreads();
  }

  int cg = blkN >> 9;                    // 0=Q,1=K,2=V — uniform per block
#pragma unroll
  for (int mi = 0; mi < 4; ++mi)
#pragma unroll
    for (int ni = 0; ni < 4; ++ni) {
      int col = blkN + wc * 64 + ni * 16 + lr;
      int c = col & 511;
#pragma unroll
      for (int j = 0; j < 4; ++j) {
        int row = blkM + wr * 64 + mi * 16 + lg * 4 + j;
        float v = acc[mi][ni][j];
        if (cg == 0) {
          Qo[(size_t)row * 512 + c] = f2bf(v * SCALE_L2E);
        } else if (cg == 1) {
          Ko[(size_t)row * 512 + c] = f2bf(v);
        } else {
          int bb = row >> 11, n = row & 2047, h = c >> 6, d = c & 63;
          // slot(key) within each 16-key group = swap bits 2 and 3
          int j4 = n & 15;
          int slot = (j4 & 3) | (((j4 >> 3) & 1) << 2) | (((j4 >> 2) & 1) << 3);
          int np = (n & ~15) | slot;
          Vo[(((size_t)(bb * HEADS + h) * DH + d) << 11) + np] = f2bf(v);
        }
      }
    }
}

// ---------- Wo GEMM: fp32 out + bias, BM=128 BN=128 (qkv-proven template) ----------
// grid 256 = 8 xcd x (8 mt x 4 nt); XCD-colocating swizzle.
__global__ __launch_bounds__(256, 2) void gemm_out_kernel(
    const unsigned short* __restrict__ A, const unsigned short* __restrict__ Wt,
    float* __restrict__ out, const float* __restrict__ bias) {
  __shared__ unsigned short Alds[128 * 64];
  __shared__ unsigned short Blds[128 * 64];
  int widx = threadIdx.x >> 6, lane = threadIdx.x & 63;
  int blk = blockIdx.x;
  int xcd = blk & 7, local = blk >> 3;   // local 0..31
  int mt = xcd * 8 + (local >> 2);       // 8 consecutive m-tiles per XCD
  int nt = local & 3;                    // 4 n-tiles of 128
  int blkM = mt * 128, blkN = nt * 128;
  int wr = widx >> 1, wc = widx & 1;
  int lr = lane & 15, lg = lane >> 4;
  int srow = lane >> 3, sc8 = lane & 7;

  f32x4 acc[4][4] = {};

  for (int kc = 0; kc < 512; kc += 64) {
#pragma unroll
    for (int i = 0; i < 4; ++i) {
      int rb = widx * 32 + i * 8;
      int row = rb + srow;
      int cs = (sc8 ^ (row & 7)) * 8;
      gload_lds16(A + (size_t)(blkM + row) * 512 + kc + cs, &Alds[rb * 64]);
      gload_lds16(Wt + (size_t)(blkN + row) * 512 + kc + cs, &Blds[rb * 64]);
    }
    __syncthreads();

#pragma unroll
    for (int kh = 0; kh < 2; ++kh) {
      bf16x8 bfr[4];
#pragma unroll
      for (int ni = 0; ni < 4; ++ni) {
        int brow = wc * 64 + ni * 16 + lr;
        bfr[ni] = *(const bf16x8*)&Blds[brow * 64 + (((kh * 4 + lg) ^ (brow & 7)) * 8)];
      }
#pragma unroll
      for (int mi = 0; mi < 4; ++mi) {
        int arow = wr * 64 + mi * 16 + lr;
        bf16x8 afr = *(const bf16x8*)&Alds[arow * 64 + (((kh * 4 + lg) ^ (arow & 7)) * 8)];
#pragma unroll
        for (int ni = 0; ni < 4; ++ni)
          acc[mi][ni] = __builtin_amdgcn_mfma_f32_16x16x32_bf16(afr, bfr[ni], acc[mi][ni], 0, 0, 0);
      }
    }
    __syncthreads();
  }

#pragma unroll
  for (int mi = 0; mi < 4; ++mi)
#pragma unroll
    for (int ni = 0; ni < 4; ++ni) {
      int col = blkN + wc * 64 + ni * 16 + lr;
#pragma unroll
      for (int j = 0; j < 4; ++j) {
        int row = blkM + wr * 64 + mi * 16 + lg * 4 + j;
        out[(size_t)row * 512 + col] = acc[mi][ni][j] + bias[col];
      }
    }
}

// ------------- flash attention, 32x32 MFMA, split-K x 64-q-rows-per-wave -------------
// R18-VERIFIED (93.5us anchor). 512 threads = 8 waves; waves 0-3: keys 0..1023,
// 4-7: keys 1024..2047. Each wave owns 64 q-rows (2 subtiles of 32). K/V fragments
// read from LDS once per chunk, shared by both q-subtiles. All o[][] accesses
// statically indexed (rule #20); merge epilogue hand-unrolled with compile-time QT.

#define AKV 64
#define NCH_S 16   // 1024 keys / 64 per stream

// stage chunk kcc into buffer `buf` of this wave's stream
#define STAGE_S(buf, kcc) do {                                            \
    unsigned short* dK = skm + (buf) * 8192 + wq * (16 * 64);             \
    gload_lds16(gkA + (size_t)(kcc) * 512, dK);                           \
    gload_lds16(gkB + (size_t)(kcc) * 512, dK + 8 * 64);                  \
    gload_lds16(gvA + (kcc), dK + 4096);                                  \
    gload_lds16(gvB + (kcc), dK + 4096 + 8 * 64);                         \
  } while (0)

// process the 64-key tile in buffer `b` for both q-subtiles (all indices static)
#define PROC(b) do {                                                      \
    f32x16 s[2][2];                                                       \
    __builtin_amdgcn_s_setprio(1);                                        \
    _Pragma("unroll")                                                     \
    for (int kt = 0; kt < 2; ++kt) {                                      \
      bf16x8 kf[4];                                                       \
      _Pragma("unroll")                                                   \
      for (int ks = 0; ks < 4; ++ks)                                      \
        kf[ks] = *(const bf16x8*)(sk + ko[kt * 4 + ks] + (b) * 8192);     \
      _Pragma("unroll")                                                   \
      for (int qt = 0; qt < 2; ++qt) {                                    \
        f32x16 z = {};                                                    \
        _Pragma("unroll")                                                 \
        for (int ks = 0; ks < 4; ++ks)                                    \
          z = __builtin_amdgcn_mfma_f32_32x32x16_bf16(kf[ks], qf[qt][ks], z, 0, 0, 0); \
        s[qt][kt] = z;                                                    \
      }                                                                   \
    }                                                                     \
    __builtin_amdgcn_s_setprio(0);                                        \
    union { unsigned w[4]; bf16x8 v; } pf[2][4];                          \
    _Pragma("unroll")                                                     \
    for (int qt = 0; qt < 2; ++qt) {                                      \
      float q4[8];                                                        \
      _Pragma("unroll")                                                   \
      for (int i = 0; i < 8; ++i)                                         \
        q4[i] = fmaxf(fmaxf(s[qt][0][i], s[qt][0][i + 8]),                \
                      fmaxf(s[qt][1][i], s[qt][1][i + 8]));               \
      float m8 = fmaxf(fmaxf(fmaxf(q4[0], q4[1]), fmaxf(q4[2], q4[3])),   \
                       fmaxf(fmaxf(q4[4], q4[5]), fmaxf(q4[6], q4[7])));  \
      m8 = fmaxf(m8, __shfl_xor(m8, 32));                                 \
      bool grow = (m8 > m0[qt] + DEFER_THR);                              \
      if (__any((int)grow)) {                                             \
        float mn = fmaxf(m0[qt], m8);                                     \
        float al = fexp2(m0[qt] - mn);                                    \
        m0[qt] = mn; l0[qt] *= al;                                        \
        _Pragma("unroll")                                                 \
        for (int dt = 0; dt < 2; ++dt)                                    \
          _Pragma("unroll")                                               \
          for (int j = 0; j < 16; ++j) o[qt][dt][j] *= al;                \
      }                                                                   \
      float rsA = 0.f, rsB = 0.f;                                         \
      _Pragma("unroll")                                                   \
      for (int d2 = 0; d2 < 4; ++d2) {                                    \
        float a0 = fexp2(s[qt][0][2 * d2] - m0[qt]);                      \
        float b0 = fexp2(s[qt][0][2 * d2 + 1] - m0[qt]);                  \
        rsA += a0 + b0;                                                   \
        pf[qt][0].w[d2] = cvt_pk_bf16(a0, b0);                            \
        float a1 = fexp2(s[qt][0][8 + 2 * d2] - m0[qt]);                  \
        float b1 = fexp2(s[qt][0][8 + 2 * d2 + 1] - m0[qt]);              \
        rsB += a1 + b1;                                                   \
        pf[qt][1].w[d2] = cvt_pk_bf16(a1, b1);                            \
        float a2 = fexp2(s[qt][1][2 * d2] - m0[qt]);                      \
        float b2 = fexp2(s[qt][1][2 * d2 + 1] - m0[qt]);                  \
        rsA += a2 + b2;                                                   \
        pf[qt][2].w[d2] = cvt_pk_bf16(a2, b2);                            \
        float a3 = fexp2(s[qt][1][8 + 2 * d2] - m0[qt]);                  \
        float b3 = fexp2(s[qt][1][8 + 2 * d2 + 1] - m0[qt]);              \
        rsB += a3 + b3;                                                   \
        pf[qt][3].w[d2] = cvt_pk_bf16(a3, b3);                            \
      }                                                                   \
      float rs = rsA + rsB;                                               \
      rs += __shfl_xor(rs, 32);                                           \
      l0[qt] += rs;                                                       \
    }                                                                     \
    __builtin_amdgcn_s_setprio(1);                                        \
    _Pragma("unroll")                                                     \
    for (int dt = 0; dt < 2; ++dt) {                                      \
      bf16x8 vf[4];                                                       \
      _Pragma("unroll")                                                   \
      for (int g = 0; g < 4; ++g)                                         \
        vf[g] = *(const bf16x8*)(sk + ko[dt * 4 + g] + 4096 + (b) * 8192);\
      _Pragma("unroll")                                                   \
      for (int qt = 0; qt < 2; ++qt) {                                    \
        f32x16 acc = o[qt][dt];                                           \
        _Pragma("unroll")                                                 \
        for (int g = 0; g < 4; ++g)                                       \
          acc = __builtin_amdgcn_mfma_f32_32x32x16_bf16(vf[g], pf[qt][g].v, acc, 0, 0, 0); \
        o[qt][dt] = acc;                                                  \
      }                                                                   \
    }                                                                     \
    __builtin_amdgcn_s_setprio(0);                                        \
  } while (0)

// merge one q-subtile (QT is a compile-time literal -> o statically indexed)
#define MERGE_QT(QT) do {                                                 \
    if (strm == 1) {                                                      \
      int base = (wq * 64 + lane) * 34;                                   \
      sm[base] = m0[QT];                                                  \
      sm[base + 1] = l0[QT];                                              \
      _Pragma("unroll")                                                   \
      for (int j = 0; j < 16; ++j) {                                      \
        sm[base + 2 + j] = o[QT][0][j];                                   \
        sm[base + 18 + j] = o[QT][1][j];                                  \
      }                                                                   \
    }                                                                     \
    __syncthreads();                                                      \
    if (strm == 0) {                                                      \
      int base = (wq * 64 + lane) * 34;                                   \
      float mB = sm[base], lB = sm[base + 1];                             \
      float mN = fmaxf(m0[QT], mB);                                       \
      float aA = fexp2(m0[QT] - mN), aB = fexp2(mB - mN);                 \
      float inv = 1.f / (l0[QT] * aA + lB * aB);                          \
      float aAi = aA * inv, aBi = aB * inv;                               \
      size_t rowb = (size_t)(b * NSEQ + qrow0 + (QT) * 32 + ql) * 512 + h * 64 + hi * 4; \
      _Pragma("unroll")                                                   \
      for (int dt = 0; dt < 2; ++dt)                                      \
        _Pragma("unroll")                                                 \
        for (int c = 0; c < 8; ++c) {                                     \
          float vlo = o[QT][dt][2 * c] * aAi + sm[base + 2 + dt * 16 + 2 * c] * aBi;     \
          float vhi = o[QT][dt][2 * c + 1] * aAi + sm[base + 2 + dt * 16 + 2 * c + 1] * aBi; \
          unsigned w = cvt_pk_bf16(vlo, vhi);                             \
          int d0 = dt * 32 + 8 * (c >> 1) + (c & 1) * 2;                  \
          *(unsigned*)(O + rowb + d0) = w;                                \
        }                                                                 \
    }                                                                     \
    __syncthreads();                                                      \
  } while (0)

__global__ __launch_bounds__(512, 2) void attn_kernel(
    const unsigned short* __restrict__ Q, const unsigned short* __restrict__ K,
    const unsigned short* __restrict__ VT, unsigned short* __restrict__ O) {
  // per-stream layout: [K buf0 | V buf0 | K buf1 | V buf1], 8KB slots; 64KB total
  __shared__ __align__(16) unsigned short SH[2][4][4096];
  int tid = threadIdx.x;
  int widx = tid >> 6, lane = tid & 63;
  int strm = widx >> 2;                // 0: keys 0..1023, 1: keys 1024..2047
  int wq = widx & 3;                   // q sub-tile within block
  int blk = blockIdx.x;                // 0..255
  int xcd = blk & 7;
  int idx = blk >> 3;                  // 0..31 within XCD
  int bh = xcd * 4 + (idx >> 3);       // 0..31 (4 bh per XCD)
  int qg = idx & 7;                    // 256-row q-group within bh
  int b = bh >> 3, h = bh & 7;
  int ql = lane & 31, hi = lane >> 5;
  int qrow0 = qg * 256 + wq * 64;      // this wave's 64 q-rows (2 subtiles of 32)

  // Q B-fragments: col q = ql, k-slice ks: d = ks*16 + hi*8 + j (pre-scaled)
  bf16x8 qf[2][4];
  {
    const unsigned short* Qp = Q + (size_t)(b * NSEQ + qrow0 + ql) * 512 + h * 64 + hi * 8;
#pragma unroll
    for (int qt = 0; qt < 2; ++qt)
#pragma unroll
      for (int ks = 0; ks < 4; ++ks)
        qf[qt][ks] = *(const bf16x8*)(Qp + (size_t)qt * 32 * 512 + ks * 16);
  }

  const unsigned short* Kg = K + (size_t)b * NSEQ * 512 + h * 64 + (size_t)strm * 1024 * 512;
  const unsigned short* Vg = VT + (size_t)bh * DH * NSEQ + strm * 1024;

  // ---- precomputed chunk-invariant addresses ----
  const unsigned short* sk = &SH[strm][0][0];   // stream base (reads)
  unsigned short* skm = &SH[strm][0][0];        // stream base (staging dest)
  int srA = wq * 16 + (lane >> 3), srB = srA + 8;
  int csA = (lane & 7) ^ (srA & 7), csB = (lane & 7) ^ (srB & 7);
  const unsigned short* gkA = Kg + (size_t)srA * 512 + csA * 8;
  const unsigned short* gkB = Kg + (size_t)srB * 512 + csB * 8;
  const unsigned short* gvA = Vg + (size_t)srA * NSEQ + csA * 8;
  const unsigned short* gvB = Vg + (size_t)srB * NSEQ + csB * 8;
  unsigned ko[8];
#pragma unroll
  for (int kt = 0; kt < 2; ++kt)
#pragma unroll
    for (int ks = 0; ks < 4; ++ks) {
      int krow = kt * 32 + ql;
      ko[kt * 4 + ks] = krow * 64 + (((ks * 2 + hi) ^ (krow & 7)) * 8);
    }

  float m0[2] = {-3.0e38f, -3.0e38f};
  float l0[2] = {0.f, 0.f};
  f32x16 o[2][2] = {};

  STAGE_S(0, 0);
  __syncthreads();
  for (int tt = 0; tt < NCH_S; tt += 2) {
    if (tt + 1 < NCH_S) STAGE_S(1, (tt + 1) * AKV);
    PROC(0);
    __syncthreads();
    if (tt + 2 < NCH_S) STAGE_S(0, (tt + 2) * AKV);
    PROC(1);
    __syncthreads();
  }

  // ---- two-phase split-K merge through LDS; QT is compile-time (rule #20) ----
  float* sm = (float*)&SH[0][0][0];
  MERGE_QT(0);
  MERGE_QT(1);
}

extern "C" void kernel_launch(void* const* d_in, const int* in_sizes, int n_in,
                              void* d_out, int out_size, void* d_ws, size_t ws_size,
                              hipStream_t stream) {
  const float* x   = (const float*)d_in[0];
  const float* z   = (const float*)d_in[1];
  const float* lxg = (const float*)d_in[2];
  const float* lxb = (const float*)d_in[3];
  const float* lzg = (const float*)d_in[4];
  const float* lzb = (const float*)d_in[5];
  const float* Wq  = (const float*)d_in[6];
  const float* Wk  = (const float*)d_in[7];
  const float* Wv  = (const float*)d_in[8];
  const float* Wz  = (const float*)d_in[9];
  const float* Wo  = (const float*)d_in[10];
  const float* bo  = (const float*)d_in[11];

  char* ws = (char*)d_ws;
  unsigned short* xm  = (unsigned short*)(ws);
  unsigned short* qb  = (unsigned short*)(ws + 8388608);
  unsigned short* kb  = (unsigned short*)(ws + 16777216);
  unsigned short* vt  = (unsigned short*)(ws + 25165824);
  unsigned short* ao  = (unsigned short*)(ws + 33554432);
  unsigned short* wqt = (unsigned short*)(ws + 41943040);   // wq,wk,wv,wo contiguous
  unsigned short* wot = (unsigned short*)(ws + 43515904);
  float*          z12 = (float*)(ws + 44040192);

  wtrans4z_kernel<<<1028, 256, 0, stream>>>(Wq, Wk, Wv, Wo, wqt, z, lzg, lzb, Wz, z12);
  xmod_kernel<<<NROWS / 4, 256, 0, stream>>>(x, lxg, lxb, z12, xm);
  gemm_qkv_kernel<<<768, 256, 0, stream>>>(xm, wqt, qb, kb, vt);
  attn_kernel<<<256, 512, 0, stream>>>(qb, kb, vt, ao);
  gemm_out_kernel<<<256, 256, 0, stream>>>(ao, wot, (float*)d_out, bo);
}

// Round 22
// 93.365 us; speedup vs baseline: 1.0234x; 1.0234x over previous
//
#include <hip/hip_runtime.h>

#define XD 512
#define HEADS 8
#define DH 64
#define NSEQ 2048
#define NBATCH 4
#define NROWS (NBATCH*NSEQ)   // 8192

#define SCALE_L2E 0.18033688011112042f   // 0.125 * log2(e)
#define DEFER_THR 4.0f

typedef __attribute__((ext_vector_type(8))) short bf16x8;
typedef __attribute__((ext_vector_type(8))) unsigned short u16x8;
typedef __attribute__((ext_vector_type(4))) float f32x4;
typedef __attribute__((ext_vector_type(16))) float f32x16;

__device__ __forceinline__ unsigned short f2bf(float f) {
  union { float f; unsigned u; } v; v.f = f;
  return (unsigned short)((v.u + 0x7fffu + ((v.u >> 16) & 1u)) >> 16);
}

__device__ __forceinline__ float fexp2(float x) {
#if __has_builtin(__builtin_amdgcn_exp2f)
  return __builtin_amdgcn_exp2f(x);
#else
  return exp2f(x);
#endif
}

__device__ __forceinline__ unsigned cvt_pk_bf16(float lo, float hi) {
  unsigned r;
  asm("v_cvt_pk_bf16_f32 %0, %1, %2" : "=v"(r) : "v"(lo), "v"(hi));
  return r;
}

// async global->LDS, 16B per lane; LDS dest must be wave-uniform base (HW adds lane*16)
__device__ __forceinline__ void gload_lds16(const unsigned short* g, unsigned short* l) {
  __builtin_amdgcn_global_load_lds(
      (const __attribute__((address_space(1))) unsigned int*)g,
      (__attribute__((address_space(3))) unsigned int*)l, 16, 0, 0);
}

// ------- merged: weight transpose (blocks 0..1023) + z path (blocks 1024..1027) -------
__global__ __launch_bounds__(256) void wtrans4z_kernel(
    const float* __restrict__ W0, const float* __restrict__ W1,
    const float* __restrict__ W2, const float* __restrict__ W3,
    unsigned short* __restrict__ dst,
    const float* __restrict__ z, const float* __restrict__ zg, const float* __restrict__ zb,
    const float* __restrict__ Wz, float* __restrict__ z12) {
  __shared__ float tile[32][33];
  int blk = blockIdx.x;
  if (blk < 1024) {
    int w = blk >> 8;                // weight (block-uniform)
    int t = blk & 255;
    int tn = t >> 4, tk = t & 15;    // 16x16 tiles of 32x32
    const float* W = (w == 0) ? W0 : (w == 1) ? W1 : (w == 2) ? W2 : W3;
    int r = threadIdx.x >> 5, c = threadIdx.x & 31;
#pragma unroll
    for (int i = 0; i < 4; ++i)
      tile[r + 8 * i][c] = W[(size_t)(tk * 32 + r + 8 * i) * 512 + tn * 32 + c];
    __syncthreads();
    unsigned short* d = dst + (size_t)w * 262144;
#pragma unroll
    for (int i = 0; i < 4; ++i)
      d[(size_t)(tn * 32 + r + 8 * i) * 512 + tk * 32 + c] = f2bf(tile[c][r + 8 * i]);
  } else {
    int bb = blk - 1024;             // batch
    int t = threadIdx.x;
    float zv[16];
    float mean = 0.f;
#pragma unroll
    for (int i = 0; i < 16; ++i) { zv[i] = z[bb * 16 + i]; mean += zv[i]; }
    mean *= (1.f / 16.f);
    float var = 0.f;
#pragma unroll
    for (int i = 0; i < 16; ++i) { float d = zv[i] - mean; var += d * d; }
    var *= (1.f / 16.f);
    float rs = rsqrtf(var + 1e-5f);
    float zn[16];
#pragma unroll
    for (int i = 0; i < 16; ++i) zn[i] = (zv[i] - mean) * rs * zg[i] + zb[i];
    for (int c = t; c < 1024; c += 256) {
      float acc = 0.f;
#pragma unroll
      for (int i = 0; i < 16; ++i) acc += zn[i] * Wz[i * 1024 + c];
      float s = acc / (1.f + __expf(-acc));   // silu
      z12[bb * 1024 + c] = s;
    }
  }
}

// ---------------- x_mod = LN(x)*z1 + z2 -> bf16 [8192,512] ----------------
__global__ __launch_bounds__(256) void xmod_kernel(
    const float* __restrict__ x, const float* __restrict__ g, const float* __restrict__ b,
    const float* __restrict__ z12, unsigned short* __restrict__ xm) {
  int wave = threadIdx.x >> 6, lane = threadIdx.x & 63;
  int row = blockIdx.x * 4 + wave;
  const float* xr = x + (size_t)row * XD;
  float4 v0 = ((const float4*)xr)[lane * 2];
  float4 v1 = ((const float4*)xr)[lane * 2 + 1];
  float vv[8] = {v0.x, v0.y, v0.z, v0.w, v1.x, v1.y, v1.z, v1.w};
  float sum = 0.f, sq = 0.f;
#pragma unroll
  for (int i = 0; i < 8; ++i) { sum += vv[i]; sq += vv[i] * vv[i]; }
#pragma unroll
  for (int o = 32; o; o >>= 1) { sum += __shfl_xor(sum, o); sq += __shfl_xor(sq, o); }
  float mean = sum * (1.f / 512.f);
  float var = sq * (1.f / 512.f) - mean * mean;
  float rs = rsqrtf(var + 1e-5f);
  int bb = row >> 11;
  const float* zz = z12 + bb * 1024;
  int c0 = lane * 8;
  u16x8 o8;
#pragma unroll
  for (int i = 0; i < 8; ++i) {
    int c = c0 + i;
    float t = (vv[i] - mean) * rs * g[c] + b[c];
    t = t * zz[c] + zz[512 + c];
    o8[i] = f2bf(t);
  }
  *(u16x8*)(xm + (size_t)row * XD + c0) = o8;
}

// ---------- fused QKV GEMM: [8192,512] @ [512,1536], BM=128 BN=128 BK=64 ----------
// R13-proven. XCD-colocating swizzle: xcd = blk&7 owns m-tiles [xcd*8, xcd*8+8).
__global__ __launch_bounds__(256, 2) void gemm_qkv_kernel(
    const unsigned short* __restrict__ A, const unsigned short* __restrict__ Wt,
    unsigned short* __restrict__ Qo, unsigned short* __restrict__ Ko,
    unsigned short* __restrict__ Vo) {
  __shared__ unsigned short Alds[128 * 64];
  __shared__ unsigned short Blds[128 * 64];
  int widx = threadIdx.x >> 6, lane = threadIdx.x & 63;
  int blk = blockIdx.x;
  int xcd = blk & 7, local = blk >> 3;   // local 0..95
  int mt = xcd * 8 + local / 12;         // 8 consecutive m-tiles per XCD
  int nt = local % 12;
  int blkM = mt * 128, blkN = nt * 128;
  int wr = widx >> 1, wc = widx & 1;
  int lr = lane & 15, lg = lane >> 4;
  int srow = lane >> 3, sc8 = lane & 7;

  f32x4 acc[4][4] = {};

  for (int kc = 0; kc < 512; kc += 64) {
#pragma unroll
    for (int i = 0; i < 4; ++i) {
      int rb = widx * 32 + i * 8;
      int row = rb + srow;
      int cs = (sc8 ^ (row & 7)) * 8;
      gload_lds16(A + (size_t)(blkM + row) * 512 + kc + cs, &Alds[rb * 64]);
      gload_lds16(Wt + (size_t)(blkN + row) * 512 + kc + cs, &Blds[rb * 64]);
    }
    __syncthreads();

#pragma unroll
    for (int kh = 0; kh < 2; ++kh) {
      bf16x8 bfr[4];
#pragma unroll
      for (int ni = 0; ni < 4; ++ni) {
        int brow = wc * 64 + ni * 16 + lr;
        bfr[ni] = *(const bf16x8*)&Blds[brow * 64 + (((kh * 4 + lg) ^ (brow & 7)) * 8)];
      }
#pragma unroll
      for (int mi = 0; mi < 4; ++mi) {
        int arow = wr * 64 + mi * 16 + lr;
        bf16x8 afr = *(const bf16x8*)&Alds[arow * 64 + (((kh * 4 + lg) ^ (arow & 7)) * 8)];
#pragma unroll
        for (int ni = 0; ni < 4; ++ni)
          acc[mi][ni] = __builtin_amdgcn_mfma_f32_16x16x32_bf16(afr, bfr[ni], acc[mi][ni], 0, 0, 0);
      }
    }
    __syncthreads();
  }

  int cg = blkN >> 9;                    // 0=Q,1=K,2=V — uniform per block
#pragma unroll
  for (int mi = 0; mi < 4; ++mi)
#pragma unroll
    for (int ni = 0; ni < 4; ++ni) {
      int col = blkN + wc * 64 + ni * 16 + lr;
      int c = col & 511;
#pragma unroll
      for (int j = 0; j < 4; ++j) {
        int row = blkM + wr * 64 + mi * 16 + lg * 4 + j;
        float v = acc[mi][ni][j];
        if (cg == 0) {
          Qo[(size_t)row * 512 + c] = f2bf(v * SCALE_L2E);
        } else if (cg == 1) {
          Ko[(size_t)row * 512 + c] = f2bf(v);
        } else {
          int bb = row >> 11, n = row & 2047, h = c >> 6, d = c & 63;
          // slot(key) within each 16-key group = swap bits 2 and 3
          int j4 = n & 15;
          int slot = (j4 & 3) | (((j4 >> 3) & 1) << 2) | (((j4 >> 2) & 1) << 3);
          int np = (n & ~15) | slot;
          Vo[(((size_t)(bb * HEADS + h) * DH + d) << 11) + np] = f2bf(v);
        }
      }
    }
}

// ---------- Wo GEMM: fp32 out + bias (R18-proven, BM=128 BN=64, XCD swizzle) ----------
__global__ __launch_bounds__(256, 2) void gemm_out_kernel(
    const unsigned short* __restrict__ A, const unsigned short* __restrict__ Wt,
    float* __restrict__ out, const float* __restrict__ bias) {
  __shared__ unsigned short Alds[128 * 64];
  __shared__ unsigned short Blds[64 * 64];
  int widx = threadIdx.x >> 6, lane = threadIdx.x & 63;
  int blk = blockIdx.x;
  int xcd = blk & 7, local = blk >> 3;   // local 0..63
  int mt = xcd * 8 + (local >> 3);       // 8 consecutive m-tiles per XCD
  int nt = local & 7;
  int blkM = mt * 128, blkN = nt * 64;
  int wr = widx >> 1, wc = widx & 1;
  int lr = lane & 15, lg = lane >> 4;
  int srow = lane >> 3, sc8 = lane & 7;

  f32x4 acc[4][2] = {};

  for (int kc = 0; kc < 512; kc += 64) {
#pragma unroll
    for (int i = 0; i < 4; ++i) {
      int rb = widx * 32 + i * 8;
      int row = rb + srow;
      int cs = (sc8 ^ (row & 7)) * 8;
      gload_lds16(A + (size_t)(blkM + row) * 512 + kc + cs, &Alds[rb * 64]);
    }
#pragma unroll
    for (int i = 0; i < 2; ++i) {
      int rb = widx * 16 + i * 8;
      int row = rb + srow;
      int cs = (sc8 ^ (row & 7)) * 8;
      gload_lds16(Wt + (size_t)(blkN + row) * 512 + kc + cs, &Blds[rb * 64]);
    }
    __syncthreads();

#pragma unroll
    for (int kh = 0; kh < 2; ++kh) {
      bf16x8 bfr[2];
#pragma unroll
      for (int ni = 0; ni < 2; ++ni) {
        int brow = wc * 32 + ni * 16 + lr;
        bfr[ni] = *(const bf16x8*)&Blds[brow * 64 + (((kh * 4 + lg) ^ (brow & 7)) * 8)];
      }
#pragma unroll
      for (int mi = 0; mi < 4; ++mi) {
        int arow = wr * 64 + mi * 16 + lr;
        bf16x8 afr = *(const bf16x8*)&Alds[arow * 64 + (((kh * 4 + lg) ^ (arow & 7)) * 8)];
#pragma unroll
        for (int ni = 0; ni < 2; ++ni)
          acc[mi][ni] = __builtin_amdgcn_mfma_f32_16x16x32_bf16(afr, bfr[ni], acc[mi][ni], 0, 0, 0);
      }
    }
    __syncthreads();
  }

#pragma unroll
  for (int mi = 0; mi < 4; ++mi)
#pragma unroll
    for (int ni = 0; ni < 2; ++ni) {
      int col = blkN + wc * 32 + ni * 16 + lr;
#pragma unroll
      for (int j = 0; j < 4; ++j) {
        int row = blkM + wr * 64 + mi * 16 + lg * 4 + j;
        out[(size_t)row * 512 + col] = acc[mi][ni][j] + bias[col];
      }
    }
}

// ------------- flash attention, 32x32 MFMA, split-K x 64-q-rows-per-wave -------------
// R18-VERIFIED (93.5us anchor). 512 threads = 8 waves; waves 0-3: keys 0..1023,
// 4-7: keys 1024..2047. Each wave owns 64 q-rows (2 subtiles of 32). K/V fragments
// read from LDS once per chunk, shared by both q-subtiles. All o[][] accesses
// statically indexed (rule #20); merge epilogue hand-unrolled with compile-time QT.

#define AKV 64
#define NCH_S 16   // 1024 keys / 64 per stream

// stage chunk kcc into buffer `buf` of this wave's stream
#define STAGE_S(buf, kcc) do {                                            \
    unsigned short* dK = skm + (buf) * 8192 + wq * (16 * 64);             \
    gload_lds16(gkA + (size_t)(kcc) * 512, dK);                           \
    gload_lds16(gkB + (size_t)(kcc) * 512, dK + 8 * 64);                  \
    gload_lds16(gvA + (kcc), dK + 4096);                                  \
    gload_lds16(gvB + (kcc), dK + 4096 + 8 * 64);                         \
  } while (0)

// process the 64-key tile in buffer `b` for both q-subtiles (all indices static)
#define PROC(b) do {                                                      \
    f32x16 s[2][2];                                                       \
    __builtin_amdgcn_s_setprio(1);                                        \
    _Pragma("unroll")                                                     \
    for (int kt = 0; kt < 2; ++kt) {                                      \
      bf16x8 kf[4];                                                       \
      _Pragma("unroll")                                                   \
      for (int ks = 0; ks < 4; ++ks)                                      \
        kf[ks] = *(const bf16x8*)(sk + ko[kt * 4 + ks] + (b) * 8192);     \
      _Pragma("unroll")                                                   \
      for (int qt = 0; qt < 2; ++qt) {                                    \
        f32x16 z = {};                                                    \
        _Pragma("unroll")                                                 \
        for (int ks = 0; ks < 4; ++ks)                                    \
          z = __builtin_amdgcn_mfma_f32_32x32x16_bf16(kf[ks], qf[qt][ks], z, 0, 0, 0); \
        s[qt][kt] = z;                                                    \
      }                                                                   \
    }                                                                     \
    __builtin_amdgcn_s_setprio(0);                                        \
    union { unsigned w[4]; bf16x8 v; } pf[2][4];                          \
    _Pragma("unroll")                                                     \
    for (int qt = 0; qt < 2; ++qt) {                                      \
      float q4[8];                                                        \
      _Pragma("unroll")                                                   \
      for (int i = 0; i < 8; ++i)                                         \
        q4[i] = fmaxf(fmaxf(s[qt][0][i], s[qt][0][i + 8]),                \
                      fmaxf(s[qt][1][i], s[qt][1][i + 8]));               \
      float m8 = fmaxf(fmaxf(fmaxf(q4[0], q4[1]), fmaxf(q4[2], q4[3])),   \
                       fmaxf(fmaxf(q4[4], q4[5]), fmaxf(q4[6], q4[7])));  \
      m8 = fmaxf(m8, __shfl_xor(m8, 32));                                 \
      bool grow = (m8 > m0[qt] + DEFER_THR);                              \
      if (__any((int)grow)) {                                             \
        float mn = fmaxf(m0[qt], m8);                                     \
        float al = fexp2(m0[qt] - mn);                                    \
        m0[qt] = mn; l0[qt] *= al;                                        \
        _Pragma("unroll")                                                 \
        for (int dt = 0; dt < 2; ++dt)                                    \
          _Pragma("unroll")                                               \
          for (int j = 0; j < 16; ++j) o[qt][dt][j] *= al;                \
      }                                                                   \
      float rsA = 0.f, rsB = 0.f;                                         \
      _Pragma("unroll")                                                   \
      for (int d2 = 0; d2 < 4; ++d2) {                                    \
        float a0 = fexp2(s[qt][0][2 * d2] - m0[qt]);                      \
        float b0 = fexp2(s[qt][0][2 * d2 + 1] - m0[qt]);                  \
        rsA += a0 + b0;                                                   \
        pf[qt][0].w[d2] = cvt_pk_bf16(a0, b0);                            \
        float a1 = fexp2(s[qt][0][8 + 2 * d2] - m0[qt]);                  \
        float b1 = fexp2(s[qt][0][8 + 2 * d2 + 1] - m0[qt]);              \
        rsB += a1 + b1;                                                   \
        pf[qt][1].w[d2] = cvt_pk_bf16(a1, b1);                            \
        float a2 = fexp2(s[qt][1][2 * d2] - m0[qt]);                      \
        float b2 = fexp2(s[qt][1][2 * d2 + 1] - m0[qt]);                  \
        rsA += a2 + b2;                                                   \
        pf[qt][2].w[d2] = cvt_pk_bf16(a2, b2);                            \
        float a3 = fexp2(s[qt][1][8 + 2 * d2] - m0[qt]);                  \
        float b3 = fexp2(s[qt][1][8 + 2 * d2 + 1] - m0[qt]);              \
        rsB += a3 + b3;                                                   \
        pf[qt][3].w[d2] = cvt_pk_bf16(a3, b3);                            \
      }                                                                   \
      float rs = rsA + rsB;                                               \
      rs += __shfl_xor(rs, 32);                                           \
      l0[qt] += rs;                                                       \
    }                                                                     \
    __builtin_amdgcn_s_setprio(1);                                        \
    _Pragma("unroll")                                                     \
    for (int dt = 0; dt < 2; ++dt) {                                      \
      bf16x8 vf[4];                                                       \
      _Pragma("unroll")                                                   \
      for (int g = 0; g < 4; ++g)                                         \
        vf[g] = *(const bf16x8*)(sk + ko[dt * 4 + g] + 4096 + (b) * 8192);\
      _Pragma("unroll")                                                   \
      for (int qt = 0; qt < 2; ++qt) {                                    \
        f32x16 acc = o[qt][dt];                                           \
        _Pragma("unroll")                                                 \
        for (int g = 0; g < 4; ++g)                                       \
          acc = __builtin_amdgcn_mfma_f32_32x32x16_bf16(vf[g], pf[qt][g].v, acc, 0, 0, 0); \
        o[qt][dt] = acc;                                                  \
      }                                                                   \
    }                                                                     \
    __builtin_amdgcn_s_setprio(0);                                        \
  } while (0)

// merge one q-subtile (QT is a compile-time literal -> o statically indexed)
#define MERGE_QT(QT) do {                                                 \
    if (strm == 1) {                                                      \
      int base = (wq * 64 + lane) * 34;                                   \
      sm[base] = m0[QT];                                                  \
      sm[base + 1] = l0[QT];                                              \
      _Pragma("unroll")                                                   \
      for (int j = 0; j < 16; ++j) {                                      \
        sm[base + 2 + j] = o[QT][0][j];                                   \
        sm[base + 18 + j] = o[QT][1][j];                                  \
      }                                                                   \
    }                                                                     \
    __syncthreads();                                                      \
    if (strm == 0) {                                                      \
      int base = (wq * 64 + lane) * 34;                                   \
      float mB = sm[base], lB = sm[base + 1];                             \
      float mN = fmaxf(m0[QT], mB);                                       \
      float aA = fexp2(m0[QT] - mN), aB = fexp2(mB - mN);                 \
      float inv = 1.f / (l0[QT] * aA + lB * aB);                          \
      float aAi = aA * inv, aBi = aB * inv;                               \
      size_t rowb = (size_t)(b * NSEQ + qrow0 + (QT) * 32 + ql) * 512 + h * 64 + hi * 4; \
      _Pragma("unroll")                                                   \
      for (int dt = 0; dt < 2; ++dt)                                      \
        _Pragma("unroll")                                                 \
        for (int c = 0; c < 8; ++c) {                                     \
          float vlo = o[QT][dt][2 * c] * aAi + sm[base + 2 + dt * 16 + 2 * c] * aBi;     \
          float vhi = o[QT][dt][2 * c + 1] * aAi + sm[base + 2 + dt * 16 + 2 * c + 1] * aBi; \
          unsigned w = cvt_pk_bf16(vlo, vhi);                             \
          int d0 = dt * 32 + 8 * (c >> 1) + (c & 1) * 2;                  \
          *(unsigned*)(O + rowb + d0) = w;                                \
        }                                                                 \
    }                                                                     \
    __syncthreads();                                                      \
  } while (0)

__global__ __launch_bounds__(512, 2) void attn_kernel(
    const unsigned short* __restrict__ Q, const unsigned short* __restrict__ K,
    const unsigned short* __restrict__ VT, unsigned short* __restrict__ O) {
  // per-stream layout: [K buf0 | V buf0 | K buf1 | V buf1], 8KB slots; 64KB total
  __shared__ __align__(16) unsigned short SH[2][4][4096];
  int tid = threadIdx.x;
  int widx = tid >> 6, lane = tid & 63;
  int strm = widx >> 2;                // 0: keys 0..1023, 1: keys 1024..2047
  int wq = widx & 3;                   // q sub-tile within block
  int blk = blockIdx.x;                // 0..255
  int xcd = blk & 7;
  int idx = blk >> 3;                  // 0..31 within XCD
  int bh = xcd * 4 + (idx >> 3);       // 0..31 (4 bh per XCD)
  int qg = idx & 7;                    // 256-row q-group within bh
  int b = bh >> 3, h = bh & 7;
  int ql = lane & 31, hi = lane >> 5;
  int qrow0 = qg * 256 + wq * 64;      // this wave's 64 q-rows (2 subtiles of 32)

  // Q B-fragments: col q = ql, k-slice ks: d = ks*16 + hi*8 + j (pre-scaled)
  bf16x8 qf[2][4];
  {
    const unsigned short* Qp = Q + (size_t)(b * NSEQ + qrow0 + ql) * 512 + h * 64 + hi * 8;
#pragma unroll
    for (int qt = 0; qt < 2; ++qt)
#pragma unroll
      for (int ks = 0; ks < 4; ++ks)
        qf[qt][ks] = *(const bf16x8*)(Qp + (size_t)qt * 32 * 512 + ks * 16);
  }

  const unsigned short* Kg = K + (size_t)b * NSEQ * 512 + h * 64 + (size_t)strm * 1024 * 512;
  const unsigned short* Vg = VT + (size_t)bh * DH * NSEQ + strm * 1024;

  // ---- precomputed chunk-invariant addresses ----
  const unsigned short* sk = &SH[strm][0][0];   // stream base (reads)
  unsigned short* skm = &SH[strm][0][0];        // stream base (staging dest)
  int srA = wq * 16 + (lane >> 3), srB = srA + 8;
  int csA = (lane & 7) ^ (srA & 7), csB = (lane & 7) ^ (srB & 7);
  const unsigned short* gkA = Kg + (size_t)srA * 512 + csA * 8;
  const unsigned short* gkB = Kg + (size_t)srB * 512 + csB * 8;
  const unsigned short* gvA = Vg + (size_t)srA * NSEQ + csA * 8;
  const unsigned short* gvB = Vg + (size_t)srB * NSEQ + csB * 8;
  unsigned ko[8];
#pragma unroll
  for (int kt = 0; kt < 2; ++kt)
#pragma unroll
    for (int ks = 0; ks < 4; ++ks) {
      int krow = kt * 32 + ql;
      ko[kt * 4 + ks] = krow * 64 + (((ks * 2 + hi) ^ (krow & 7)) * 8);
    }

  float m0[2] = {-3.0e38f, -3.0e38f};
  float l0[2] = {0.f, 0.f};
  f32x16 o[2][2] = {};

  STAGE_S(0, 0);
  __syncthreads();
  for (int tt = 0; tt < NCH_S; tt += 2) {
    if (tt + 1 < NCH_S) STAGE_S(1, (tt + 1) * AKV);
    PROC(0);
    __syncthreads();
    if (tt + 2 < NCH_S) STAGE_S(0, (tt + 2) * AKV);
    PROC(1);
    __syncthreads();
  }

  // ---- two-phase split-K merge through LDS; QT is compile-time (rule #20) ----
  float* sm = (float*)&SH[0][0][0];
  MERGE_QT(0);
  MERGE_QT(1);
}

extern "C" void kernel_launch(void* const* d_in, const int* in_sizes, int n_in,
                              void* d_out, int out_size, void* d_ws, size_t ws_size,
                              hipStream_t stream) {
  const float* x   = (const float*)d_in[0];
  const float* z   = (const float*)d_in[1];
  const float* lxg = (const float*)d_in[2];
  const float* lxb = (const float*)d_in[3];
  const float* lzg = (const float*)d_in[4];
  const float* lzb = (const float*)d_in[5];
  const float* Wq  = (const float*)d_in[6];
  const float* Wk  = (const float*)d_in[7];
  const float* Wv  = (const float*)d_in[8];
  const float* Wz  = (const float*)d_in[9];
  const float* Wo  = (const float*)d_in[10];
  const float* bo  = (const float*)d_in[11];

  char* ws = (char*)d_ws;
  unsigned short* xm  = (unsigned short*)(ws);
  unsigned short* qb  = (unsigned short*)(ws + 8388608);
  unsigned short* kb  = (unsigned short*)(ws + 16777216);
  unsigned short* vt  = (unsigned short*)(ws + 25165824);
  unsigned short* ao  = (unsigned short*)(ws + 33554432);
  unsigned short* wqt = (unsigned short*)(ws + 41943040);   // wq,wk,wv,wo contiguous
  unsigned short* wot = (unsigned short*)(ws + 43515904);
  float*          z12 = (float*)(ws + 44040192);

  wtrans4z_kernel<<<1028, 256, 0, stream>>>(Wq, Wk, Wv, Wo, wqt, z, lzg, lzb, Wz, z12);
  xmod_kernel<<<NROWS / 4, 256, 0, stream>>>(x, lxg, lxb, z12, xm);
  gemm_qkv_kernel<<<768, 256, 0, stream>>>(xm, wqt, qb, kb, vt);
  attn_kernel<<<256, 512, 0, stream>>>(qb, kb, vt, ao);
  gemm_out_kernel<<<512, 256, 0, stream>>>(ao, wot, (float*)d_out, bo);
}